// Round 7
// baseline (797.764 us; speedup 1.0000x reference)
//
#include <hip/hip_runtime.h>
#include <math.h>

// Problem constants (fixed by reference)
#define GRIDN   14
#define BOXN    2
#define LABELN  20
#define ALL_BOX 10          // 5*BOXN
#define CCH     30          // ALL_BOX + LABELN channels per cell

// R14: two-phase compaction. R13's lesson: the m13-shape stream was never
// tested clean -- the inline obj-gather (~0.7 hits/wave-iter -> divergent
// ~200-instr cell_loss + ~30 scattered loads nearly every iteration) was
// the new bottleneck (VALUBusy 30%, 2.08 TB/s). R14 decouples it:
//   A) pure stream: branchless conf^2 sum over preds + obj-detect over
//      truths; obj cell indices compacted into a d_ws worklist (~64K
//      atomics total, ~10 masked instrs on the rare path). No LDS, no
//      barriers, no gather. The undecorated m13 float4 pattern at last.
//   B) gather: grid-stride over the worklist, one lane per obj cell,
//      validated cell_loss verbatim minus the double-counted conf term.
//      ~30 MB of scattered reads against a fully L3-resident (192 MB)
//      working set, paid once on 64K items instead of 6M stream-iters.
// Kernel-boundary ordering on the stream makes the worklist coherent.
#define NBLK  2048
#define NTHR  256
#define GSTRIDE (NBLK * NTHR)
#define GBLK2 512               // gather-phase blocks

typedef float vfloat4 __attribute__((ext_vector_type(4)));

__global__ void yolo_zero_kernel(float* out, int n, int* wcnt) {
    int i = blockIdx.x * blockDim.x + threadIdx.x;
    if (i < n) out[i] = 0.0f;
    if (i == 0) *wcnt = 0;
}

// Validated per-cell loss math (absmax 0 in rounds 1-13). Unchanged.
__device__ __forceinline__ float cell_loss(const float* p, const float* t) {
#pragma clang fp contract(off)
    const float CELL = (float)(1.0 / (double)GRIDN);

    const float tx = t[0], ty = t[1], tw = t[2], th_ = t[3], tconf = t[4];
    const bool obj = tconf > 0.0f;

    const float tcx = CELL * tx, tcy = CELL * ty;
    const float thx = tw * 0.5f, thy = th_ * 0.5f;
    const float tltx = tcx - thx, tlty = tcy - thy;
    const float trbx = tcx + thx, trby = tcy + thy;
    const float ta = (trbx - tltx) * (trby - tlty);

    float iou[BOXN], conf[BOXN];
#pragma unroll
    for (int b = 0; b < BOXN; ++b) {
        const float bx = p[b * 5 + 0], by = p[b * 5 + 1];
        const float bw = p[b * 5 + 2], bh = p[b * 5 + 3];
        conf[b] = p[b * 5 + 4];
        const float pcx = CELL * bx, pcy = CELL * by;
        const float phx = bw * 0.5f, phy = bh * 0.5f;
        const float pltx = pcx - phx, plty = pcy - phy;
        const float prbx = pcx + phx, prby = pcy + phy;
        const float ltx = fmaxf(pltx, tltx), lty = fmaxf(plty, tlty);
        const float rbx = fminf(prbx, trbx), rby = fminf(prby, trby);
        const float whx = fmaxf(rbx - ltx, 0.0f);
        const float why = fmaxf(rby - lty, 0.0f);
        const float inter = whx * why;
        const float pa = (prbx - pltx) * (prby - plty);
        iou[b] = inter / (pa + ta - inter);
    }

    const float max_iou = fmaxf(iou[0], iou[1]);
    bool r1;
    if (iou[0] == iou[1]) r1 = !(conf[0] >= conf[1]);
    else                  r1 = !(iou[0] > iou[1]);

    const float rx = r1 ? p[5] : p[0];
    const float ry = r1 ? p[6] : p[1];
    const float rw = r1 ? p[7] : p[2];
    const float rh = r1 ? p[8] : p[3];
    const float rc = r1 ? p[9] : p[4];

    const float dcx = rx - tx;
    const float dcy = ry - ty;
    const float center = dcx * dcx + dcy * dcy;

    const float dsx = sqrtf(rw) - sqrtf(tw);
    const float dsy = sqrtf(rh) - sqrtf(th_);
    const float size = dsx * dsx + dsy * dsy;

    const float dconf = rc - max_iou;
    const float conf_resp = dconf * dconf;

    const float c_other = r1 ? conf[0] : conf[1];
    const float conf_noresp = c_other * c_other;

    const float conf_noobj = conf[0] * conf[0] + conf[1] * conf[1];

    float label = 0.0f;
#pragma unroll
    for (int k = ALL_BOX; k < CCH; ++k) {
        const float d = p[k] - t[k];
        label += d * d;
    }

    const float w  = obj ? 1.0f : 0.0f;
    const float nw = obj ? 0.0f : 1.0f;
    return w * (5.0f * (center + size) + conf_resp + 0.5f * conf_noresp + label)
         + nw * (0.5f * conf_noobj);
}

// Phase A: pure dual stream + compaction. No LDS tile, no barriers.
__global__ __launch_bounds__(256) void yolo_stream_kernel(
    const float* __restrict__ preds,
    const float* __restrict__ truths,
    float* __restrict__ out,
    int* __restrict__ wcnt,
    int* __restrict__ wlist,
    int wcap,
    int nf4)
{
#pragma clang fp contract(off)
    __shared__ float wsum[4];

    const int tid  = threadIdx.x;
    const int wave = tid >> 6;
    const int lane = tid & 63;
    const int gid  = blockIdx.x * NTHR + tid;

    const vfloat4* pp = (const vfloat4*)preds;
    const vfloat4* tp = (const vfloat4*)truths;

    float acc = 0.0f;

    for (int idx = gid; idx < nf4; idx += GSTRIDE) {
        const vfloat4 pv = pp[idx];
        const vfloat4 tv = tp[idx];
        const int f  = idx * 4;        // flat float index (< 2^25, safe)
        const int c0 = f % 30;         // channel of element 0 (magic-mul)

        // preds: all-cells 0.5*conf^2 (channels 4 and 9). Branchless.
#pragma unroll
        for (int j = 0; j < 4; ++j) {
            int c = c0 + j; if (c >= 30) c -= 30;
            const float v = pv[j];
            acc += (c == 4 || c == 9) ? 0.5f * v * v : 0.0f;
        }

        // truths: obj-detect on channel 4 -> compact index only (~10
        // masked instrs, ~0.7 lanes/wave-iter). The heavy math moved to
        // the gather kernel.
#pragma unroll
        for (int j = 0; j < 4; ++j) {
            int c = c0 + j; if (c >= 30) c -= 30;
            if (c == 4 && tv[j] > 0.0f) {
                const int slot = atomicAdd(wcnt, 1);
                if (slot < wcap) wlist[slot] = (f + j) / 30;
            }
        }
    }

#pragma unroll
    for (int off = 32; off > 0; off >>= 1) acc += __shfl_down(acc, off, 64);
    if (lane == 0) wsum[wave] = acc;
    __syncthreads();
    if (tid == 0) {
        const float s = (wsum[0] + wsum[1]) + (wsum[2] + wsum[3]);
        atomicAdd(out, s * (1.0f / 4096.0f));
    }
}

// Phase B: one lane per obj cell. L3-resident gather (~30 MB total).
__global__ __launch_bounds__(256) void yolo_gather_kernel(
    const float* __restrict__ preds,
    const float* __restrict__ truths,
    float* __restrict__ out,
    const int* __restrict__ wcnt,
    const int* __restrict__ wlist,
    int wcap)
{
#pragma clang fp contract(off)
    __shared__ float wsum[4];

    const int tid  = threadIdx.x;
    const int wave = tid >> 6;
    const int lane = tid & 63;
    const int gid  = blockIdx.x * NTHR + tid;

    int n = *wcnt;
    if (n > wcap) n = wcap;

    float acc = 0.0f;
    for (int i = gid; i < n; i += GBLK2 * NTHR) {
        const int cell = wlist[i];
        const float* p = preds  + cell * CCH;
        const float* t = truths + cell * CCH;
        const float p4 = p[4], p9 = p[9];
        // Phase A already added 0.5*(p4^2+p9^2) for EVERY cell; obj cells
        // must not carry that term -> subtract it alongside the obj loss.
        acc += cell_loss(p, t) - 0.5f * (p4 * p4 + p9 * p9);
    }

#pragma unroll
    for (int off = 32; off > 0; off >>= 1) acc += __shfl_down(acc, off, 64);
    if (lane == 0) wsum[wave] = acc;
    __syncthreads();
    if (tid == 0) {
        const float s = (wsum[0] + wsum[1]) + (wsum[2] + wsum[3]);
        atomicAdd(out, s * (1.0f / 4096.0f));
    }
}

extern "C" void kernel_launch(void* const* d_in, const int* in_sizes, int n_in,
                              void* d_out, int out_size, void* d_ws, size_t ws_size,
                              hipStream_t stream) {
    const float* preds  = (const float*)d_in[0];
    const float* truths = (const float*)d_in[1];
    float* out = (float*)d_out;

    const int nf4 = in_sizes[0] / 4;           // 6,021,120 float4 per tensor

    // Workspace layout: [0..15] counter (16B-aligned), rest = worklist.
    int* wcnt  = (int*)d_ws;
    int* wlist = (int*)d_ws + 4;
    const long long cap_ll = ((long long)ws_size - 16) / 4;
    const int wcap = cap_ll > 0x7fffffff ? 0x7fffffff : (int)cap_ll;

    yolo_zero_kernel<<<(out_size + 255) / 256, 256, 0, stream>>>(out, out_size, wcnt);
    yolo_stream_kernel<<<NBLK, NTHR, 0, stream>>>(preds, truths, out,
                                                  wcnt, wlist, wcap, nf4);
    yolo_gather_kernel<<<GBLK2, NTHR, 0, stream>>>(preds, truths, out,
                                                   wcnt, wlist, wcap);
}

// Round 9
// 217.149 us; speedup vs baseline: 3.6738x; 3.6738x over previous
//
#include <hip/hip_runtime.h>
#include <math.h>

// Problem constants (fixed by reference)
#define GRIDN   14
#define BOXN    2
#define LABELN  20
#define ALL_BOX 10          // 5*BOXN
#define CCH     30          // ALL_BOX + LABELN channels per cell

// R15 (resubmit; round 8 was an infra failure -- "container failed twice",
// no compile/test signal). Fused atomic-free split-loss kernel.
// History: staged/barriered schedules (R7-R12) all pin at 2.4-2.8 TB/s.
// R13 (split loss, gather inlined in stream): gather divergence poisons
// every stream iteration -> 92 us. R14 (compaction via per-lane global
// atomicAdd to ONE counter): ~64K contended same-address atomics serialize
// the whole machine -> 650 us, VALUBusy 1.3% (Guideline 12 violation).
// Key realization: the two partial sums are INDEPENDENT -- no worklist
// needed at all:
//   loss = SUM_allcells 0.5*(p4^2+p9^2)        [reads PREDS only, streaming]
//        + SUM_objcells (cell_loss - 0.5*(p4^2+p9^2))  [detect via truths ch4]
// Phase 1 (per thread): pure grid-stride float4 preds stream (the m13
//   pattern, undecorated: no LDS, no barriers, no atomics, no divergence).
// Phase 2 (per thread): one lane per cell, read t[30c+4] (one 64B line per
//   cell, fully parallel); ~8% obj lanes run the validated cell_loss.
//   Divergent path amortizes ~5 active lanes/wave over 0.8M cells instead
//   of poisoning 6M stream iterations.
// One atomic per block (out), nothing else shared.
#define NBLK  2048
#define NTHR  256
#define NTHREADS (NBLK * NTHR)

typedef float vfloat4 __attribute__((ext_vector_type(4)));

__global__ void yolo_zero_kernel(float* out, int n) {
    int i = blockIdx.x * blockDim.x + threadIdx.x;
    if (i < n) out[i] = 0.0f;
}

// Validated per-cell loss math (absmax 0 in rounds 1-14). Unchanged.
__device__ __forceinline__ float cell_loss(const float* p, const float* t) {
#pragma clang fp contract(off)
    const float CELL = (float)(1.0 / (double)GRIDN);

    const float tx = t[0], ty = t[1], tw = t[2], th_ = t[3], tconf = t[4];
    const bool obj = tconf > 0.0f;

    const float tcx = CELL * tx, tcy = CELL * ty;
    const float thx = tw * 0.5f, thy = th_ * 0.5f;
    const float tltx = tcx - thx, tlty = tcy - thy;
    const float trbx = tcx + thx, trby = tcy + thy;
    const float ta = (trbx - tltx) * (trby - tlty);

    float iou[BOXN], conf[BOXN];
#pragma unroll
    for (int b = 0; b < BOXN; ++b) {
        const float bx = p[b * 5 + 0], by = p[b * 5 + 1];
        const float bw = p[b * 5 + 2], bh = p[b * 5 + 3];
        conf[b] = p[b * 5 + 4];
        const float pcx = CELL * bx, pcy = CELL * by;
        const float phx = bw * 0.5f, phy = bh * 0.5f;
        const float pltx = pcx - phx, plty = pcy - phy;
        const float prbx = pcx + phx, prby = pcy + phy;
        const float ltx = fmaxf(pltx, tltx), lty = fmaxf(plty, tlty);
        const float rbx = fminf(prbx, trbx), rby = fminf(prby, trby);
        const float whx = fmaxf(rbx - ltx, 0.0f);
        const float why = fmaxf(rby - lty, 0.0f);
        const float inter = whx * why;
        const float pa = (prbx - pltx) * (prby - plty);
        iou[b] = inter / (pa + ta - inter);
    }

    const float max_iou = fmaxf(iou[0], iou[1]);
    bool r1;
    if (iou[0] == iou[1]) r1 = !(conf[0] >= conf[1]);
    else                  r1 = !(iou[0] > iou[1]);

    const float rx = r1 ? p[5] : p[0];
    const float ry = r1 ? p[6] : p[1];
    const float rw = r1 ? p[7] : p[2];
    const float rh = r1 ? p[8] : p[3];
    const float rc = r1 ? p[9] : p[4];

    const float dcx = rx - tx;
    const float dcy = ry - ty;
    const float center = dcx * dcx + dcy * dcy;

    const float dsx = sqrtf(rw) - sqrtf(tw);
    const float dsy = sqrtf(rh) - sqrtf(th_);
    const float size = dsx * dsx + dsy * dsy;

    const float dconf = rc - max_iou;
    const float conf_resp = dconf * dconf;

    const float c_other = r1 ? conf[0] : conf[1];
    const float conf_noresp = c_other * c_other;

    const float conf_noobj = conf[0] * conf[0] + conf[1] * conf[1];

    float label = 0.0f;
#pragma unroll
    for (int k = ALL_BOX; k < CCH; ++k) {
        const float d = p[k] - t[k];
        label += d * d;
    }

    const float w  = obj ? 1.0f : 0.0f;
    const float nw = obj ? 0.0f : 1.0f;
    return w * (5.0f * (center + size) + conf_resp + 0.5f * conf_noresp + label)
         + nw * (0.5f * conf_noobj);
}

__global__ __launch_bounds__(256) void yolo_loss_kernel(
    const float* __restrict__ preds,
    const float* __restrict__ truths,
    float* __restrict__ out,
    int nf4,                        // float4 count of preds (6,021,120)
    int ncells)                     // 802,816
{
#pragma clang fp contract(off)
    __shared__ float wsum[4];

    const int tid  = threadIdx.x;
    const int wave = tid >> 6;
    const int lane = tid & 63;
    const int gid  = blockIdx.x * NTHR + tid;

    const vfloat4* pp = (const vfloat4*)preds;

    float acc = 0.0f;

    // ---- Phase 1: pure preds stream (m13 pattern, undecorated) ----------
    // All-cells 0.5*conf^2 (channels 4 and 9 of each 30-float cell).
    for (int idx = gid; idx < nf4; idx += NTHREADS) {
        const vfloat4 pv = pp[idx];
        const int f  = idx * 4;        // flat float index (< 2^25, safe)
        const int c0 = f % 30;         // channel of element 0 (magic-mul)
#pragma unroll
        for (int j = 0; j < 4; ++j) {
            int c = c0 + j; if (c >= 30) c -= 30;
            const float v = pv[j];
            acc += (c == 4 || c == 9) ? 0.5f * v * v : 0.0f;
        }
    }

    // ---- Phase 2: obj-cell scan (one lane per cell) ---------------------
    // Independent 4B probes (one 64B line per cell); ~8% of lanes take the
    // divergent validated-loss path, amortized ~5 lanes per wave.
    for (int cell = gid; cell < ncells; cell += NTHREADS) {
        const float tconf = truths[cell * CCH + 4];
        if (tconf > 0.0f) {
            const float* p = preds  + cell * CCH;
            const float* t = truths + cell * CCH;
            const float p4 = p[4], p9 = p[9];
            // Phase 1 added 0.5*(p4^2+p9^2) for EVERY cell; obj cells must
            // not carry that term -> subtract alongside the obj loss.
            acc += cell_loss(p, t) - 0.5f * (p4 * p4 + p9 * p9);
        }
    }

    // Per-thread acc -> wave shuffle -> LDS across waves -> one atomic/block.
#pragma unroll
    for (int off = 32; off > 0; off >>= 1) acc += __shfl_down(acc, off, 64);
    if (lane == 0) wsum[wave] = acc;
    __syncthreads();
    if (tid == 0) {
        const float s = (wsum[0] + wsum[1]) + (wsum[2] + wsum[3]);
        atomicAdd(out, s * (1.0f / 4096.0f));
    }
}

extern "C" void kernel_launch(void* const* d_in, const int* in_sizes, int n_in,
                              void* d_out, int out_size, void* d_ws, size_t ws_size,
                              hipStream_t stream) {
    const float* preds  = (const float*)d_in[0];
    const float* truths = (const float*)d_in[1];
    float* out = (float*)d_out;

    const int nf4    = in_sizes[0] / 4;        // 6,021,120 float4 (preds)
    const int ncells = in_sizes[0] / CCH;      // 802,816 cells

    yolo_zero_kernel<<<(out_size + 255) / 256, 256, 0, stream>>>(out, out_size);
    yolo_loss_kernel<<<NBLK, NTHR, 0, stream>>>(preds, truths, out, nf4, ncells);
}